// Round 3
// baseline (385.384 us; speedup 1.0000x reference)
//
#include <hip/hip_runtime.h>
#include <hip/hip_bf16.h>
#include <stdint.h>
#include <math.h>

// NT-Xent contrastive loss, N=4096, D=1024, 2N=8192 rows.
// Pipeline: knorm (normalize + bf16 cast) -> ksim (bf16 MFMA GEMM + exp + rowsum)
//           -> kfinal (exact fp32 positives + lse + mean).

#define NROWS 8192      // 2N
#define HALFN 4096      // N
#define DIM   1024      // D
#define INV_T 14.285714285714286f   // 1/0.07; also the fixed LSE shift C (sim <= 1/T)

typedef __bf16 bf16x8 __attribute__((ext_vector_type(8)));
typedef float  f32x4  __attribute__((ext_vector_type(4)));

__device__ __forceinline__ unsigned short f2bf(float x) {
  union { float f; uint32_t u; } c; c.f = x;
  uint32_t u = c.u;
  return (unsigned short)((u + 0x7FFFu + ((u >> 16) & 1u)) >> 16);
}

__device__ __forceinline__ void gload16(const void* g, void* lds) {
  __builtin_amdgcn_global_load_lds(
      (const __attribute__((address_space(1))) unsigned int*)g,
      (__attribute__((address_space(3))) unsigned int*)lds,
      16, 0, 0);
}

// ---------------- kernel A: row L2-normalize + bf16 convert ----------------
__global__ __launch_bounds__(256) void knorm(const float* __restrict__ zi,
                                             const float* __restrict__ zj,
                                             __bf16* __restrict__ znb,
                                             float* __restrict__ rnorm) {
  int r = blockIdx.x;
  const float* z = (r < HALFN) ? (zi + (size_t)r * DIM)
                               : (zj + (size_t)(r - HALFN) * DIM);
  int t = threadIdx.x;
  float4 v = ((const float4*)z)[t];                 // 256 threads * float4 = 1024
  float ss = v.x*v.x + v.y*v.y + v.z*v.z + v.w*v.w;
  for (int m = 32; m; m >>= 1) ss += __shfl_xor(ss, m);
  __shared__ float wss[4];
  if ((t & 63) == 0) wss[t >> 6] = ss;
  __syncthreads();
  float nrm = sqrtf(wss[0] + wss[1] + wss[2] + wss[3]);
  nrm = fmaxf(nrm, 1e-8f);
  float rn = 1.0f / nrm;
  if (t == 0) rnorm[r] = rn;
  ushort4 o;
  o.x = f2bf(v.x * rn); o.y = f2bf(v.y * rn);
  o.z = f2bf(v.z * rn); o.w = f2bf(v.w * rn);
  ((ushort4*)znb)[(size_t)r * (DIM / 4) + t] = o;
}

// ---------------- kernel C: sim GEMM + exp + per-row sums ----------------
#define BM 128
#define BN 128
#define BK 64
#define KTILES (DIM / BK)   // 16

__global__ __launch_bounds__(256) void ksim(const __bf16* __restrict__ znb,
                                            float* __restrict__ rowsum) {
  __shared__ __align__(16) __bf16 As[BM * BK];   // 16 KB, linear [row][k]
  __shared__ __align__(16) __bf16 Bs[BN * BK];   // 16 KB

  // bijective XCD swizzle: 4096 blocks, 8 XCDs, 512 per XCD
  unsigned bid = blockIdx.x;
  unsigned swz = (bid & 7u) * 512u + (bid >> 3);
  unsigned rb = swz >> 6;          // 0..63 row tile
  unsigned cb = swz & 63u;         // 0..63 col tile

  int t = threadIdx.x;
  int w = t >> 6, l = t & 63;
  int wr = w >> 1, wc = w & 1;     // 2x2 wave grid, each wave 64x64
  int lr = l & 15, lg = l >> 4;

  f32x4 acc[4][4] = {};

  const __bf16* Aor = znb + (size_t)rb * BM * DIM;
  const __bf16* Bor = znb + (size_t)cb * BN * DIM;

  for (int kt = 0; kt < KTILES; ++kt) {
    __syncthreads();               // previous compute done reading LDS
    int k0 = kt * BK;
#pragma unroll
    for (int i = 0; i < 4; ++i) {
      int c = (w * 4 + i) * 64 + l;          // 16B-chunk id 0..1023
      int row = c >> 3, col8 = c & 7;        // tile row, 8-elem column group
      const __bf16* ga = Aor + (size_t)row * DIM + k0 + col8 * 8;
      const __bf16* gb = Bor + (size_t)row * DIM + k0 + col8 * 8;
      // wave-uniform LDS base + lane*16 (linear dest, m97 pattern)
      gload16(ga, (char*)As + (w * 4 + i) * 1024);
      gload16(gb, (char*)Bs + (w * 4 + i) * 1024);
    }
    __syncthreads();               // vmcnt(0) drain: tile resident
#pragma unroll
    for (int kk = 0; kk < 2; ++kk) {
      bf16x8 af[4], bg[4];
#pragma unroll
      for (int m = 0; m < 4; ++m) {
        int row = wr * 64 + m * 16 + lr;
        af[m] = *(const bf16x8*)((const char*)As + row * 128 + (kk * 4 + lg) * 16);
      }
#pragma unroll
      for (int n = 0; n < 4; ++n) {
        int col = wc * 64 + n * 16 + lr;
        bg[n] = *(const bf16x8*)((const char*)Bs + col * 128 + (kk * 4 + lg) * 16);
      }
#pragma unroll
      for (int m = 0; m < 4; ++m)
#pragma unroll
        for (int n = 0; n < 4; ++n)
          acc[m][n] = __builtin_amdgcn_mfma_f32_16x16x32_bf16(af[m], bg[n], acc[m][n], 0, 0, 0);
    }
  }

  // epilogue: e = exp((dot-1)/T) = exp2((dot-1)*s2); diag masked; per-row sums
  const float s2 = INV_T * 1.442695040888963f;
  int grow_base = (int)(rb * BM) + wr * 64;
  int gcol_base = (int)(cb * BN) + wc * 64;
#pragma unroll
  for (int m = 0; m < 4; ++m) {
    float s[4] = {0.f, 0.f, 0.f, 0.f};
#pragma unroll
    for (int n = 0; n < 4; ++n) {
      int gcol = gcol_base + n * 16 + lr;    // C/D: col = lane&15
#pragma unroll
      for (int j = 0; j < 4; ++j) {
        int grow = grow_base + m * 16 + lg * 4 + j;   // row = (lane>>4)*4 + j
        float e = exp2f(fmaf(acc[m][n][j], s2, -s2));
        if (grow == gcol) e = 0.f;           // diagonal -inf mask
        s[j] += e;
      }
    }
#pragma unroll
    for (int j = 0; j < 4; ++j) {
      float v = s[j];
      v += __shfl_xor(v, 1);
      v += __shfl_xor(v, 2);
      v += __shfl_xor(v, 4);
      v += __shfl_xor(v, 8);
      if (lr == 0)
        atomicAdd(rowsum + grow_base + m * 16 + lg * 4 + j, v);
    }
  }
}

// ---------------- kernel D: exact positives + lse + mean ----------------
__global__ __launch_bounds__(256) void kfinal(const float* __restrict__ zi,
                                              const float* __restrict__ zj,
                                              const float* __restrict__ rnorm,
                                              const float* __restrict__ rowsum,
                                              float* __restrict__ out) {
  int t = threadIdx.x;
  int w = t >> 6, l = t & 63;
  int r = blockIdx.x * 4 + w;          // one wave per row
  int p = r ^ HALFN;                   // NT-Xent partner (N is a power of 2)
  const float* zr = (r < HALFN) ? zi + (size_t)r * DIM : zj + (size_t)(r - HALFN) * DIM;
  const float* zp = (p < HALFN) ? zi + (size_t)p * DIM : zj + (size_t)(p - HALFN) * DIM;
  float dot = 0.f;
#pragma unroll
  for (int j = 0; j < 4; ++j) {
    float4 a = ((const float4*)zr)[j * 64 + l];
    float4 b = ((const float4*)zp)[j * 64 + l];
    dot += a.x*b.x + a.y*b.y + a.z*b.z + a.w*b.w;
  }
  for (int m = 32; m; m >>= 1) dot += __shfl_xor(dot, m);
  __shared__ float part[4];
  if (l == 0) {
    float lse = logf(rowsum[r]) + INV_T;
    float pos = dot * rnorm[r] * rnorm[p] * INV_T;
    part[w] = (lse - pos) * (1.0f / (float)NROWS);
  }
  __syncthreads();
  if (t == 0) atomicAdd(out, part[0] + part[1] + part[2] + part[3]);
}

// ---------------- launch ----------------
extern "C" void kernel_launch(void* const* d_in, const int* in_sizes, int n_in,
                              void* d_out, int out_size, void* d_ws, size_t ws_size,
                              hipStream_t stream) {
  const float* zi = (const float*)d_in[0];
  const float* zj = (const float*)d_in[1];
  float* out = (float*)d_out;
  char* ws = (char*)d_ws;
  __bf16* znb   = (__bf16*)ws;                                   // 16 MB
  float*  rnorm = (float*)(ws + (size_t)NROWS * DIM * 2);        // 32 KB
  float*  rowsum= (float*)(ws + (size_t)NROWS * DIM * 2 + NROWS * 4);

  (void)hipMemsetAsync(rowsum, 0, NROWS * sizeof(float), stream);
  (void)hipMemsetAsync(out, 0, sizeof(float), stream);

  knorm<<<NROWS, 256, 0, stream>>>(zi, zj, znb, rnorm);
  ksim<<<64 * 64, 256, 0, stream>>>(znb, rowsum);
  kfinal<<<NROWS / 4, 256, 0, stream>>>(zi, zj, rnorm, rowsum, out);
}

// Round 4
// 317.600 us; speedup vs baseline: 1.2134x; 1.2134x over previous
//
#include <hip/hip_runtime.h>
#include <hip/hip_bf16.h>
#include <stdint.h>
#include <math.h>

// NT-Xent contrastive loss, N=4096, D=1024, 2N=8192 rows.
// knorm (normalize + bf16) -> ksim (256^2-tile deep-pipelined bf16 MFMA GEMM
//   + exp + rowsum) -> kfinal (exact fp32 positives + lse + mean).

#define NROWS 8192
#define HALFN 4096
#define DIM   1024
#define INV_T 14.285714285714286f   // 1/0.07; fixed LSE shift C (sim <= 1/T)

typedef __bf16 bf16x8 __attribute__((ext_vector_type(8)));
typedef float  f32x4  __attribute__((ext_vector_type(4)));

__device__ __forceinline__ unsigned short f2bf(float x) {
  union { float f; uint32_t u; } c; c.f = x;
  uint32_t u = c.u;
  return (unsigned short)((u + 0x7FFFu + ((u >> 16) & 1u)) >> 16);
}

__device__ __forceinline__ void gload16(const void* g, void* lds) {
  __builtin_amdgcn_global_load_lds(
      (const __attribute__((address_space(1))) unsigned int*)g,
      (__attribute__((address_space(3))) unsigned int*)lds,
      16, 0, 0);
}

// ---------------- kernel A: row L2-normalize + bf16 convert ----------------
__global__ __launch_bounds__(256) void knorm(const float* __restrict__ zi,
                                             const float* __restrict__ zj,
                                             __bf16* __restrict__ znb,
                                             float* __restrict__ rnorm) {
  int r = blockIdx.x;
  const float* z = (r < HALFN) ? (zi + (size_t)r * DIM)
                               : (zj + (size_t)(r - HALFN) * DIM);
  int t = threadIdx.x;
  float4 v = ((const float4*)z)[t];
  float ss = v.x*v.x + v.y*v.y + v.z*v.z + v.w*v.w;
  for (int m = 32; m; m >>= 1) ss += __shfl_xor(ss, m);
  __shared__ float wss[4];
  if ((t & 63) == 0) wss[t >> 6] = ss;
  __syncthreads();
  float nrm = sqrtf(wss[0] + wss[1] + wss[2] + wss[3]);
  nrm = fmaxf(nrm, 1e-8f);
  float rn = 1.0f / nrm;
  if (t == 0) rnorm[r] = rn;
  ushort4 o;
  o.x = f2bf(v.x * rn); o.y = f2bf(v.y * rn);
  o.z = f2bf(v.z * rn); o.w = f2bf(v.w * rn);
  ((ushort4*)znb)[(size_t)r * (DIM / 4) + t] = o;
}

// ---------------- kernel C: 256^2 deep-pipelined sim GEMM ----------------
// BM=BN=256, BK=64, 8 waves (2x4), per-wave 128x64 output.
// LDS: 2 x (A 32KB + B 32KB) = 128KB, XOR-swizzled (chunk ^= row&7).
// Schedule per K-tile: ds_read all frags -> lgkmcnt(0)+barrier ->
//   stage tile t+2 into freed buffer (8 gload_lds) -> 64 MFMA (hides loads)
//   -> vmcnt(8)+barrier (tile t+1 resident). Counted vmcnt, never 0 in-loop.
#define BK 64
#define KT 16   // DIM/BK

__global__ __launch_bounds__(512, 2) void ksim(const __bf16* __restrict__ znb,
                                               float* __restrict__ rowsum) {
  __shared__ __align__(16) char smem[131072];   // [2][A 32KB | B 32KB]

  // bijective XCD swizzle: 1024 blocks, 8 XCDs, 128 per XCD
  unsigned bid = blockIdx.x;
  unsigned swz = (bid & 7u) * 128u + (bid >> 3);
  unsigned rb = swz >> 5;          // 0..31 row tile
  unsigned cb = swz & 31u;         // 0..31 col tile

  int t = threadIdx.x;
  int w = t >> 6, l = t & 63;
  int wm = w >> 2, wn = w & 3;     // 2x4 wave grid; wave owns 128x64
  int lr = l & 15, lg = l >> 4;
  int lr7 = lr & 7;

  const __bf16* Aor = znb + (size_t)rb * 256 * DIM;
  const __bf16* Bor = znb + (size_t)cb * 256 * DIM;

  // staging lane geometry: lane l -> local row l>>3, swizzled src chunk (l&7)^(l>>3)
  int srow = l >> 3;
  int sck  = (l & 7) ^ srow;

  f32x4 acc[8][4] = {};

#define STAGE(P, K0)                                                        \
  {                                                                         \
    char* bA = smem + (P) * 65536;                                          \
    char* bB = bA + 32768;                                                  \
    _Pragma("unroll")                                                       \
    for (int j = 0; j < 4; ++j) {                                           \
      int row = (w * 4 + j) * 8 + srow;                                     \
      gload16(Aor + (size_t)row * DIM + (K0) + sck * 8, bA + (w*4+j)*1024); \
      gload16(Bor + (size_t)row * DIM + (K0) + sck * 8, bB + (w*4+j)*1024); \
    }                                                                       \
  }

  // prologue: tiles 0,1
  STAGE(0, 0)
  STAGE(1, BK)
  asm volatile("s_waitcnt vmcnt(8)" ::: "memory");   // tile 0 resident
  __builtin_amdgcn_s_barrier();

  for (int kt = 0; kt < KT; ++kt) {
    int p = kt & 1;
    const char* bA = smem + p * 65536;
    const char* bB = bA + 32768;

    // read ALL fragments for this K-tile (swizzled addresses)
    bf16x8 a0[8], a1[8], b0[4], b1[4];
#pragma unroll
    for (int m = 0; m < 8; ++m) {
      int row = wm * 128 + m * 16 + lr;
      a0[m] = *(const bf16x8*)(bA + row * 128 + ((lg     ^ lr7) * 16));
      a1[m] = *(const bf16x8*)(bA + row * 128 + (((4+lg) ^ lr7) * 16));
    }
#pragma unroll
    for (int n = 0; n < 4; ++n) {
      int row = wn * 64 + n * 16 + lr;
      b0[n] = *(const bf16x8*)(bB + row * 128 + ((lg     ^ lr7) * 16));
      b1[n] = *(const bf16x8*)(bB + row * 128 + (((4+lg) ^ lr7) * 16));
    }
    asm volatile("s_waitcnt lgkmcnt(0)" ::: "memory"); // reads retired
    __builtin_amdgcn_sched_barrier(0);
    __builtin_amdgcn_s_barrier();                      // buffer p free

    // stage tile kt+2 into buffer p; lands under the MFMAs below
    STAGE(p, ((kt + 2) & 15) * BK)
    __builtin_amdgcn_sched_barrier(0);

    __builtin_amdgcn_s_setprio(1);
#pragma unroll
    for (int m = 0; m < 8; ++m)
#pragma unroll
      for (int n = 0; n < 4; ++n)
        acc[m][n] = __builtin_amdgcn_mfma_f32_16x16x32_bf16(a0[m], b0[n], acc[m][n], 0, 0, 0);
#pragma unroll
    for (int m = 0; m < 8; ++m)
#pragma unroll
      for (int n = 0; n < 4; ++n)
        acc[m][n] = __builtin_amdgcn_mfma_f32_16x16x32_bf16(a1[m], b1[n], acc[m][n], 0, 0, 0);
    __builtin_amdgcn_s_setprio(0);

    asm volatile("s_waitcnt vmcnt(8)" ::: "memory");   // tile kt+1 resident
    __builtin_amdgcn_s_barrier();
  }
#undef STAGE

  // epilogue: e = exp2((dot-1)*s2), diag masked, per-row sums -> atomics
  const float s2 = INV_T * 1.442695040888963f;
  int growb = (int)(rb * 256) + wm * 128;
  int gcolb = (int)(cb * 256) + wn * 64;
#pragma unroll
  for (int m = 0; m < 8; ++m) {
    float s[4] = {0.f, 0.f, 0.f, 0.f};
#pragma unroll
    for (int n = 0; n < 4; ++n) {
      int gcol = gcolb + n * 16 + lr;                  // C/D: col = lane&15
#pragma unroll
      for (int j = 0; j < 4; ++j) {
        int grow = growb + m * 16 + lg * 4 + j;        // row = (lane>>4)*4+j
        float e = exp2f(fmaf(acc[m][n][j], s2, -s2));
        if (grow == gcol) e = 0.f;
        s[j] += e;
      }
    }
#pragma unroll
    for (int j = 0; j < 4; ++j) {
      float v = s[j];
      v += __shfl_xor(v, 1);
      v += __shfl_xor(v, 2);
      v += __shfl_xor(v, 4);
      v += __shfl_xor(v, 8);
      if (lr == 0)
        atomicAdd(rowsum + growb + m * 16 + lg * 4 + j, v);
    }
  }
}

// ---------------- kernel D: exact positives + lse + mean ----------------
__global__ __launch_bounds__(256) void kfinal(const float* __restrict__ zi,
                                              const float* __restrict__ zj,
                                              const float* __restrict__ rnorm,
                                              const float* __restrict__ rowsum,
                                              float* __restrict__ out) {
  int t = threadIdx.x;
  int w = t >> 6, l = t & 63;
  int r = blockIdx.x * 4 + w;
  int p = r ^ HALFN;
  const float* zr = (r < HALFN) ? zi + (size_t)r * DIM : zj + (size_t)(r - HALFN) * DIM;
  const float* zp = (p < HALFN) ? zi + (size_t)p * DIM : zj + (size_t)(p - HALFN) * DIM;
  float dot = 0.f;
#pragma unroll
  for (int j = 0; j < 4; ++j) {
    float4 a = ((const float4*)zr)[j * 64 + l];
    float4 b = ((const float4*)zp)[j * 64 + l];
    dot += a.x*b.x + a.y*b.y + a.z*b.z + a.w*b.w;
  }
  for (int m = 32; m; m >>= 1) dot += __shfl_xor(dot, m);
  __shared__ float part[4];
  if (l == 0) {
    float lse = logf(rowsum[r]) + INV_T;
    float pos = dot * rnorm[r] * rnorm[p] * INV_T;
    part[w] = (lse - pos) * (1.0f / (float)NROWS);
  }
  __syncthreads();
  if (t == 0) atomicAdd(out, part[0] + part[1] + part[2] + part[3]);
}

// ---------------- launch ----------------
extern "C" void kernel_launch(void* const* d_in, const int* in_sizes, int n_in,
                              void* d_out, int out_size, void* d_ws, size_t ws_size,
                              hipStream_t stream) {
  const float* zi = (const float*)d_in[0];
  const float* zj = (const float*)d_in[1];
  float* out = (float*)d_out;
  char* ws = (char*)d_ws;
  __bf16* znb   = (__bf16*)ws;                                   // 16 MB
  float*  rnorm = (float*)(ws + (size_t)NROWS * DIM * 2);        // 32 KB
  float*  rowsum= (float*)(ws + (size_t)NROWS * DIM * 2 + NROWS * 4);

  (void)hipMemsetAsync(rowsum, 0, NROWS * sizeof(float), stream);
  (void)hipMemsetAsync(out, 0, sizeof(float), stream);

  knorm<<<NROWS, 256, 0, stream>>>(zi, zj, znb, rnorm);
  ksim<<<32 * 32, 512, 0, stream>>>(znb, rowsum);
  kfinal<<<NROWS / 4, 256, 0, stream>>>(zi, zj, rnorm, rowsum, out);
}

// Round 5
// 292.690 us; speedup vs baseline: 1.3167x; 1.0851x over previous
//
#include <hip/hip_runtime.h>
#include <hip/hip_bf16.h>
#include <stdint.h>
#include <math.h>

// NT-Xent contrastive loss, N=4096, D=1024, 2N=8192 rows.
// knorm (normalize + bf16) -> ksim (256^2 8-phase pipelined bf16 MFMA GEMM
//   + exp + rowsum) -> kfinal (exact fp32 positives per pair + lse + mean).

#define NROWS 8192
#define HALFN 4096
#define DIM   1024
#define INV_T 14.285714285714286f   // 1/0.07; fixed LSE shift C (sim <= 1/T)

typedef __bf16 bf16x8 __attribute__((ext_vector_type(8)));
typedef float  f32x4  __attribute__((ext_vector_type(4)));

__device__ __forceinline__ unsigned short f2bf(float x) {
  union { float f; uint32_t u; } c; c.f = x;
  uint32_t u = c.u;
  return (unsigned short)((u + 0x7FFFu + ((u >> 16) & 1u)) >> 16);
}

__device__ __forceinline__ void gload16(const void* g, void* lds) {
  __builtin_amdgcn_global_load_lds(
      (const __attribute__((address_space(1))) unsigned int*)g,
      (__attribute__((address_space(3))) unsigned int*)lds,
      16, 0, 0);
}

// ---------------- kernel A: row L2-normalize + bf16 convert ----------------
__global__ __launch_bounds__(256) void knorm(const float* __restrict__ zi,
                                             const float* __restrict__ zj,
                                             __bf16* __restrict__ znb,
                                             float* __restrict__ rnorm) {
  int r = blockIdx.x;
  const float* z = (r < HALFN) ? (zi + (size_t)r * DIM)
                               : (zj + (size_t)(r - HALFN) * DIM);
  int t = threadIdx.x;
  float4 v = ((const float4*)z)[t];
  float ss = v.x*v.x + v.y*v.y + v.z*v.z + v.w*v.w;
  for (int m = 32; m; m >>= 1) ss += __shfl_xor(ss, m);
  __shared__ float wss[4];
  if ((t & 63) == 0) wss[t >> 6] = ss;
  __syncthreads();
  float nrm = sqrtf(wss[0] + wss[1] + wss[2] + wss[3]);
  nrm = fmaxf(nrm, 1e-8f);
  float rn = 1.0f / nrm;
  if (t == 0) rnorm[r] = rn;
  ushort4 o;
  o.x = f2bf(v.x * rn); o.y = f2bf(v.y * rn);
  o.z = f2bf(v.z * rn); o.w = f2bf(v.w * rn);
  ((ushort4*)znb)[(size_t)r * (DIM / 4) + t] = o;
}

// ---------------- kernel C: 256^2 8-phase pipelined sim GEMM ----------------
// BM=BN=256, BK=64, 8 waves (2x4), per-wave 128x64 out, acc[8][4].
// LDS 128KB: A-buf0 @0, A-buf1 @32K, B-buf0 @64K, B-buf1 @96K; each 32KB =
// [256 rows][64 K] bf16, row stride 128B, chunk XOR-swizzle (chunk ^= row&7).
// Iteration it processes K-tiles (2it [buf0], 2it+1 [buf1]) in 8 phases.
// Phase = {ds_read subtile (+12 at P0/P4) | stage 1 half-tile (2 gload_lds) |
//          barrier | lgkmcnt(0)+sched_barrier | setprio1 16xMFMA setprio0 |
//          barrier}. vmcnt(4) ONLY at end of P3/P7 (counted, never drained).
// Stage ledger: P0,P1: A-buf1 <- tile 2it+1 (read this iter P4-P7);
//   P2,P3: B-buf0 <- 2it+2; P4,P5: A-buf0 <- 2it+2; P6,P7: B-buf1 <- 2it+3.

__device__ __forceinline__ void stageh(const __bf16* gpanel, int k0, char* ldsb,
                                       int rh, int w, int srow, int sck) {
#pragma unroll
  for (int j = 0; j < 2; ++j) {
    int rowu = rh + w * 16 + j * 8;                       // wave-uniform row base
    gload16(gpanel + (size_t)(rowu + srow) * DIM + k0 + sck * 8,
            ldsb + rowu * 128);
  }
}

__device__ __forceinline__ void rda2(bf16x8 (&af)[2][2], const char* ab, int q,
                                     int ar, int sw0, int sw1) {
#pragma unroll
  for (int mm = 0; mm < 2; ++mm) {
    const char* base = ab + ar + (2 * q + mm) * 2048;
    af[mm][0] = *(const bf16x8*)(base + sw0);
    af[mm][1] = *(const bf16x8*)(base + sw1);
  }
}

__device__ __forceinline__ void rdb8(bf16x8 (&bf)[4][2], const char* bb,
                                     int br, int sw0, int sw1) {
#pragma unroll
  for (int n = 0; n < 4; ++n) {
    const char* base = bb + br + n * 2048;
    bf[n][0] = *(const bf16x8*)(base + sw0);
    bf[n][1] = *(const bf16x8*)(base + sw1);
  }
}

template <int Q>
__device__ __forceinline__ void mfma16(f32x4 (&acc)[8][4], bf16x8 (&af)[2][2],
                                       bf16x8 (&bf)[4][2]) {
#pragma unroll
  for (int s = 0; s < 2; ++s)
#pragma unroll
    for (int mm = 0; mm < 2; ++mm)
#pragma unroll
      for (int n = 0; n < 4; ++n)
        acc[2 * Q + mm][n] = __builtin_amdgcn_mfma_f32_16x16x32_bf16(
            af[mm][s], bf[n][s], acc[2 * Q + mm][n], 0, 0, 0);
}

__global__ __launch_bounds__(512, 2) void ksim(const __bf16* __restrict__ znb,
                                               float* __restrict__ rowsum) {
  __shared__ __align__(16) char smem[131072];
  constexpr int AB0 = 0, AB1 = 32768, BB0 = 65536, BB1 = 98304;

  // bijective XCD swizzle: 1024 blocks, 8 XCDs, 128 per XCD
  unsigned bid = blockIdx.x;
  unsigned swz = (bid & 7u) * 128u + (bid >> 3);
  unsigned rb = swz >> 5, cb = swz & 31u;

  int t = threadIdx.x;
  int w = t >> 6, l = t & 63;
  int wm = w >> 2, wn = w & 3;          // 2x4 wave grid; wave owns 128x64
  int lr = l & 15, lg = l >> 4, lr7 = l & 7;
  int srow = l >> 3;
  int sck = (l & 7) ^ srow;             // pre-swizzled source chunk

  const __bf16* Aor = znb + (size_t)rb * 256 * DIM;
  const __bf16* Bor = znb + (size_t)cb * 256 * DIM;

  int ar  = (wm * 128 + lr) * 128;      // A frag row-base (bytes)
  int br  = (wn * 64 + lr) * 128;       // B frag row-base (bytes)
  int sw0 = ((lg) ^ lr7) * 16;          // ksub 0 swizzled chunk offset
  int sw1 = ((4 + lg) ^ lr7) * 16;      // ksub 1

  f32x4 acc[8][4] = {};
  bf16x8 af[2][2], bf[4][2];

#define BAR __builtin_amdgcn_s_barrier()
#define LGKM0 { asm volatile("s_waitcnt lgkmcnt(0)" ::: "memory"); \
                __builtin_amdgcn_sched_barrier(0); }
#define VM4 asm volatile("s_waitcnt vmcnt(4)" ::: "memory")
#define P1() __builtin_amdgcn_s_setprio(1)
#define P0() __builtin_amdgcn_s_setprio(0)

  // prologue: A-buf0,B-buf0 <- tile0; B-buf1 <- tile1 (A-buf1 staged in-loop)
  stageh(Aor, 0, smem + AB0, 0, w, srow, sck);
  stageh(Aor, 0, smem + AB0, 128, w, srow, sck);
  stageh(Bor, 0, smem + BB0, 0, w, srow, sck);
  stageh(Bor, 0, smem + BB0, 128, w, srow, sck);
  stageh(Bor, 64, smem + BB1, 0, w, srow, sck);
  stageh(Bor, 64, smem + BB1, 128, w, srow, sck);
  VM4;                                   // A0,B0 landed; B1's 4 in flight
  BAR;

  for (int it = 0; it < 8; ++it) {
    int kA1 = (2 * it + 1) * 64;         // A-buf1 target (this iter's T1)
    int kT2 = ((2 * it + 2) & 15) * 64;  // buf0 targets (next iter T0)
    int kT3 = ((2 * it + 3) & 15) * 64;  // B-buf1 target (next iter T1)

    // P0
    rdb8(bf, smem + BB0, br, sw0, sw1);
    rda2(af, smem + AB0, 0, ar, sw0, sw1);
    stageh(Aor, kA1, smem + AB1, 0, w, srow, sck);
    BAR; LGKM0; P1(); mfma16<0>(acc, af, bf); P0(); BAR;
    // P1
    rda2(af, smem + AB0, 1, ar, sw0, sw1);
    stageh(Aor, kA1, smem + AB1, 128, w, srow, sck);
    BAR; LGKM0; P1(); mfma16<1>(acc, af, bf); P0(); BAR;
    // P2
    rda2(af, smem + AB0, 2, ar, sw0, sw1);
    stageh(Bor, kT2, smem + BB0, 0, w, srow, sck);
    BAR; LGKM0; P1(); mfma16<2>(acc, af, bf); P0(); BAR;
    // P3
    rda2(af, smem + AB0, 3, ar, sw0, sw1);
    stageh(Bor, kT2, smem + BB0, 128, w, srow, sck);
    BAR; LGKM0; P1(); mfma16<3>(acc, af, bf); P0(); VM4; BAR;
    // P4
    rdb8(bf, smem + BB1, br, sw0, sw1);
    rda2(af, smem + AB1, 0, ar, sw0, sw1);
    stageh(Aor, kT2, smem + AB0, 0, w, srow, sck);
    BAR; LGKM0; P1(); mfma16<0>(acc, af, bf); P0(); BAR;
    // P5
    rda2(af, smem + AB1, 1, ar, sw0, sw1);
    stageh(Aor, kT2, smem + AB0, 128, w, srow, sck);
    BAR; LGKM0; P1(); mfma16<1>(acc, af, bf); P0(); BAR;
    // P6
    rda2(af, smem + AB1, 2, ar, sw0, sw1);
    stageh(Bor, kT3, smem + BB1, 0, w, srow, sck);
    BAR; LGKM0; P1(); mfma16<2>(acc, af, bf); P0(); BAR;
    // P7
    rda2(af, smem + AB1, 3, ar, sw0, sw1);
    stageh(Bor, kT3, smem + BB1, 128, w, srow, sck);
    BAR; LGKM0; P1(); mfma16<3>(acc, af, bf); P0(); VM4; BAR;
  }
#undef BAR
#undef LGKM0
#undef VM4
#undef P1
#undef P0

  // epilogue: e = exp2((dot-1)*s2), diag masked, per-row sums -> atomics
  const float s2 = INV_T * 1.442695040888963f;
  int growb = (int)(rb * 256) + wm * 128;
  int gcolb = (int)(cb * 256) + wn * 64;
#pragma unroll
  for (int m = 0; m < 8; ++m) {
    float s[4] = {0.f, 0.f, 0.f, 0.f};
#pragma unroll
    for (int n = 0; n < 4; ++n) {
      int gcol = gcolb + n * 16 + lr;                    // C/D: col = lane&15
#pragma unroll
      for (int j = 0; j < 4; ++j) {
        int grow = growb + m * 16 + lg * 4 + j;          // row = (lane>>4)*4+j
        float e = exp2f(fmaf(acc[m][n][j], s2, -s2));
        if (grow == gcol) e = 0.f;
        s[j] += e;
      }
    }
#pragma unroll
    for (int j = 0; j < 4; ++j) {
      float v = s[j];
      v += __shfl_xor(v, 1);
      v += __shfl_xor(v, 2);
      v += __shfl_xor(v, 4);
      v += __shfl_xor(v, 8);
      if (lr == 0)
        atomicAdd(rowsum + growb + m * 16 + lg * 4 + j, v);
    }
  }
}

// ---------------- kernel D: one dot per pair + lse + mean ----------------
__global__ __launch_bounds__(256) void kfinal(const float* __restrict__ zi,
                                              const float* __restrict__ zj,
                                              const float* __restrict__ rnorm,
                                              const float* __restrict__ rowsum,
                                              float* __restrict__ out) {
  int t = threadIdx.x;
  int w = t >> 6, l = t & 63;
  int r = blockIdx.x * 4 + w;            // pair index 0..HALFN-1
  const float* zr = zi + (size_t)r * DIM;
  const float* zp = zj + (size_t)r * DIM;
  float dot = 0.f;
#pragma unroll
  for (int j = 0; j < 4; ++j) {
    float4 a = ((const float4*)zr)[j * 64 + l];
    float4 b = ((const float4*)zp)[j * 64 + l];
    dot += a.x*b.x + a.y*b.y + a.z*b.z + a.w*b.w;
  }
  for (int m = 32; m; m >>= 1) dot += __shfl_xor(dot, m);
  __shared__ float part[4];
  if (l == 0) {
    float lse_r = logf(rowsum[r]) + INV_T;
    float lse_p = logf(rowsum[r + HALFN]) + INV_T;
    float pos = dot * rnorm[r] * rnorm[r + HALFN] * INV_T;
    part[w] = (lse_r + lse_p - 2.0f * pos) * (1.0f / (float)NROWS);
  }
  __syncthreads();
  if (t == 0) atomicAdd(out, part[0] + part[1] + part[2] + part[3]);
}

// ---------------- launch ----------------
extern "C" void kernel_launch(void* const* d_in, const int* in_sizes, int n_in,
                              void* d_out, int out_size, void* d_ws, size_t ws_size,
                              hipStream_t stream) {
  const float* zi = (const float*)d_in[0];
  const float* zj = (const float*)d_in[1];
  float* out = (float*)d_out;
  char* ws = (char*)d_ws;
  __bf16* znb   = (__bf16*)ws;                                   // 16 MB
  float*  rnorm = (float*)(ws + (size_t)NROWS * DIM * 2);        // 32 KB
  float*  rowsum= (float*)(ws + (size_t)NROWS * DIM * 2 + NROWS * 4);

  (void)hipMemsetAsync(rowsum, 0, NROWS * sizeof(float), stream);
  (void)hipMemsetAsync(out, 0, sizeof(float), stream);

  knorm<<<NROWS, 256, 0, stream>>>(zi, zj, znb, rnorm);
  ksim<<<32 * 32, 512, 0, stream>>>(znb, rowsum);
  kfinal<<<HALFN / 4, 256, 0, stream>>>(zi, zj, rnorm, rowsum, out);
}

// Round 7
// 285.909 us; speedup vs baseline: 1.3479x; 1.0237x over previous
//
#include <hip/hip_runtime.h>
#include <hip/hip_bf16.h>
#include <stdint.h>
#include <math.h>

// NT-Xent contrastive loss, N=4096, D=1024, 2N=8192 rows.
// knorm (normalize + bf16) -> ksim (256^2 8-phase pipelined bf16 MFMA GEMM
//   + exp + rowsum) -> kfinal (exact fp32 positives per pair + lse + mean).

#define NROWS 8192
#define HALFN 4096
#define DIM   1024
#define INV_T 14.285714285714286f   // 1/0.07; fixed LSE shift C (sim <= 1/T)

typedef __bf16 bf16x8 __attribute__((ext_vector_type(8)));
typedef float  f32x4  __attribute__((ext_vector_type(4)));

__device__ __forceinline__ unsigned short f2bf(float x) {
  union { float f; uint32_t u; } c; c.f = x;
  uint32_t u = c.u;
  return (unsigned short)((u + 0x7FFFu + ((u >> 16) & 1u)) >> 16);
}

__device__ __forceinline__ void gload16(const void* g, void* lds) {
  __builtin_amdgcn_global_load_lds(
      (const __attribute__((address_space(1))) unsigned int*)g,
      (__attribute__((address_space(3))) unsigned int*)lds,
      16, 0, 0);
}

// ---------------- kernel A: row L2-normalize + bf16 convert ----------------
__global__ __launch_bounds__(256) void knorm(const float* __restrict__ zi,
                                             const float* __restrict__ zj,
                                             __bf16* __restrict__ znb,
                                             float* __restrict__ rnorm) {
  int r = blockIdx.x;
  const float* z = (r < HALFN) ? (zi + (size_t)r * DIM)
                               : (zj + (size_t)(r - HALFN) * DIM);
  int t = threadIdx.x;
  float4 v = ((const float4*)z)[t];
  float ss = v.x*v.x + v.y*v.y + v.z*v.z + v.w*v.w;
  for (int m = 32; m; m >>= 1) ss += __shfl_xor(ss, m);
  __shared__ float wss[4];
  if ((t & 63) == 0) wss[t >> 6] = ss;
  __syncthreads();
  float nrm = sqrtf(wss[0] + wss[1] + wss[2] + wss[3]);
  nrm = fmaxf(nrm, 1e-8f);
  float rn = 1.0f / nrm;
  if (t == 0) rnorm[r] = rn;
  ushort4 o;
  o.x = f2bf(v.x * rn); o.y = f2bf(v.y * rn);
  o.z = f2bf(v.z * rn); o.w = f2bf(v.w * rn);
  ((ushort4*)znb)[(size_t)r * (DIM / 4) + t] = o;
}

// ---------------- kernel C: 256^2 8-phase pipelined sim GEMM ----------------
// BM=BN=256, BK=64, 8 waves (2x4), per-wave 128x64 out, acc[8][4].
// LDS 128KB: A-buf0 @0, A-buf1 @32K, B-buf0 @64K, B-buf1 @96K; each 32KB =
// [256 rows][64 K] bf16, row stride 128B, chunk XOR-swizzle (chunk ^= row&7).
// Phase = {ds_read subtile | stage half-tile (2 gload_lds) | barrier |
//          setprio1 16xMFMA setprio0 | barrier}. NO explicit lgkmcnt /
// sched_barrier: compiler-tracked ds_read->MFMA waits give the fine
// interleave (m97/r109); hard fences were the round-5 regression (m141).
// vmcnt(4) ONLY at end of P3/P7 (counted, never drained in-loop).
// Stage ledger: P0,P1: A-buf1 <- tile 2it+1 (read this iter P4-P7);
//   P2,P3: B-buf0 <- 2it+2; P4,P5: A-buf0 <- 2it+2; P6,P7: B-buf1 <- 2it+3.

__device__ __forceinline__ void stageh(const __bf16* gpanel, int k0, char* ldsb,
                                       int rh, int w, int srow, int sck) {
#pragma unroll
  for (int j = 0; j < 2; ++j) {
    int rowu = rh + w * 16 + j * 8;                       // wave-uniform row base
    gload16(gpanel + (size_t)(rowu + srow) * DIM + k0 + sck * 8,
            ldsb + rowu * 128);
  }
}

__device__ __forceinline__ void rda2(bf16x8 (&af)[2][2], const char* ab, int q,
                                     int ar, int sw0, int sw1) {
#pragma unroll
  for (int mm = 0; mm < 2; ++mm) {
    const char* base = ab + ar + (2 * q + mm) * 2048;
    af[mm][0] = *(const bf16x8*)(base + sw0);
    af[mm][1] = *(const bf16x8*)(base + sw1);
  }
}

__device__ __forceinline__ void rdb8(bf16x8 (&bf)[4][2], const char* bb,
                                     int br, int sw0, int sw1) {
#pragma unroll
  for (int n = 0; n < 4; ++n) {
    const char* base = bb + br + n * 2048;
    bf[n][0] = *(const bf16x8*)(base + sw0);
    bf[n][1] = *(const bf16x8*)(base + sw1);
  }
}

template <int Q>
__device__ __forceinline__ void mfma16(f32x4 (&acc)[8][4], bf16x8 (&af)[2][2],
                                       bf16x8 (&bf)[4][2]) {
#pragma unroll
  for (int s = 0; s < 2; ++s)
#pragma unroll
    for (int mm = 0; mm < 2; ++mm)
#pragma unroll
      for (int n = 0; n < 4; ++n)
        acc[2 * Q + mm][n] = __builtin_amdgcn_mfma_f32_16x16x32_bf16(
            af[mm][s], bf[n][s], acc[2 * Q + mm][n], 0, 0, 0);
}

__global__ __launch_bounds__(512, 2) void ksim(const __bf16* __restrict__ znb,
                                               float* __restrict__ rowsum) {
  __shared__ __align__(16) char smem[131072];
  constexpr int AB0 = 0, AB1 = 32768, BB0 = 65536, BB1 = 98304;

  // bijective XCD swizzle: 1024 blocks, 8 XCDs, 128 per XCD
  unsigned bid = blockIdx.x;
  unsigned swz = (bid & 7u) * 128u + (bid >> 3);
  unsigned rb = swz >> 5, cb = swz & 31u;

  int t = threadIdx.x;
  int w = t >> 6, l = t & 63;
  int wm = w >> 2, wn = w & 3;          // 2x4 wave grid; wave owns 128x64
  int lr = l & 15, lg = l >> 4, lr7 = l & 7;
  int srow = l >> 3;
  int sck = (l & 7) ^ srow;             // pre-swizzled source chunk

  const __bf16* Aor = znb + (size_t)rb * 256 * DIM;
  const __bf16* Bor = znb + (size_t)cb * 256 * DIM;

  int ar  = (wm * 128 + lr) * 128;      // A frag row-base (bytes)
  int br  = (wn * 64 + lr) * 128;       // B frag row-base (bytes)
  int sw0 = ((lg) ^ lr7) * 16;          // ksub 0 swizzled chunk offset
  int sw1 = ((4 + lg) ^ lr7) * 16;      // ksub 1

  f32x4 acc[8][4] = {};
  bf16x8 af[2][2], bf[4][2];

#define BAR __builtin_amdgcn_s_barrier()
#define VM4 asm volatile("s_waitcnt vmcnt(4)" ::: "memory")
#define P1() __builtin_amdgcn_s_setprio(1)
#define P0() __builtin_amdgcn_s_setprio(0)

  // prologue: A-buf0,B-buf0 <- tile0; B-buf1 <- tile1 (A-buf1 staged in-loop)
  stageh(Aor, 0, smem + AB0, 0, w, srow, sck);
  stageh(Aor, 0, smem + AB0, 128, w, srow, sck);
  stageh(Bor, 0, smem + BB0, 0, w, srow, sck);
  stageh(Bor, 0, smem + BB0, 128, w, srow, sck);
  stageh(Bor, 64, smem + BB1, 0, w, srow, sck);
  stageh(Bor, 64, smem + BB1, 128, w, srow, sck);
  VM4;                                   // A0,B0 landed; B1's 4 in flight
  BAR;

  for (int it = 0; it < 8; ++it) {
    int kA1 = (2 * it + 1) * 64;         // A-buf1 target (this iter's T1)
    int kT2 = ((2 * it + 2) & 15) * 64;  // buf0 targets (next iter T0)
    int kT3 = ((2 * it + 3) & 15) * 64;  // B-buf1 target (next iter T1)

    // P0
    rdb8(bf, smem + BB0, br, sw0, sw1);
    rda2(af, smem + AB0, 0, ar, sw0, sw1);
    stageh(Aor, kA1, smem + AB1, 0, w, srow, sck);
    BAR; P1(); mfma16<0>(acc, af, bf); P0(); BAR;
    // P1
    rda2(af, smem + AB0, 1, ar, sw0, sw1);
    stageh(Aor, kA1, smem + AB1, 128, w, srow, sck);
    BAR; P1(); mfma16<1>(acc, af, bf); P0(); BAR;
    // P2
    rda2(af, smem + AB0, 2, ar, sw0, sw1);
    stageh(Bor, kT2, smem + BB0, 0, w, srow, sck);
    BAR; P1(); mfma16<2>(acc, af, bf); P0(); BAR;
    // P3
    rda2(af, smem + AB0, 3, ar, sw0, sw1);
    stageh(Bor, kT2, smem + BB0, 128, w, srow, sck);
    BAR; P1(); mfma16<3>(acc, af, bf); P0(); VM4; BAR;
    // P4
    rdb8(bf, smem + BB1, br, sw0, sw1);
    rda2(af, smem + AB1, 0, ar, sw0, sw1);
    stageh(Aor, kT2, smem + AB0, 0, w, srow, sck);
    BAR; P1(); mfma16<0>(acc, af, bf); P0(); BAR;
    // P5
    rda2(af, smem + AB1, 1, ar, sw0, sw1);
    stageh(Aor, kT2, smem + AB0, 128, w, srow, sck);
    BAR; P1(); mfma16<1>(acc, af, bf); P0(); BAR;
    // P6
    rda2(af, smem + AB1, 2, ar, sw0, sw1);
    stageh(Bor, kT3, smem + BB1, 0, w, srow, sck);
    BAR; P1(); mfma16<2>(acc, af, bf); P0(); BAR;
    // P7
    rda2(af, smem + AB1, 3, ar, sw0, sw1);
    stageh(Bor, kT3, smem + BB1, 128, w, srow, sck);
    BAR; P1(); mfma16<3>(acc, af, bf); P0(); VM4; BAR;
  }
#undef BAR
#undef VM4
#undef P1
#undef P0

  // epilogue: e = exp2((dot-1)*s2), diag masked, per-row sums -> atomics
  const float s2 = INV_T * 1.442695040888963f;
  int growb = (int)(rb * 256) + wm * 128;
  int gcolb = (int)(cb * 256) + wn * 64;
#pragma unroll
  for (int m = 0; m < 8; ++m) {
    float s[4] = {0.f, 0.f, 0.f, 0.f};
#pragma unroll
    for (int n = 0; n < 4; ++n) {
      int gcol = gcolb + n * 16 + lr;                    // C/D: col = lane&15
#pragma unroll
      for (int j = 0; j < 4; ++j) {
        int grow = growb + m * 16 + lg * 4 + j;          // row = (lane>>4)*4+j
        float e = exp2f(fmaf(acc[m][n][j], s2, -s2));
        if (grow == gcol) e = 0.f;
        s[j] += e;
      }
    }
#pragma unroll
    for (int j = 0; j < 4; ++j) {
      float v = s[j];
      v += __shfl_xor(v, 1);
      v += __shfl_xor(v, 2);
      v += __shfl_xor(v, 4);
      v += __shfl_xor(v, 8);
      if (lr == 0)
        atomicAdd(rowsum + growb + m * 16 + lg * 4 + j, v);
    }
  }
}

// ---------------- kernel D: positives + lse + mean, low atomic contention --
// 256 blocks x 4 sweeps; ONE same-address atomic per block (was 1024).
__global__ __launch_bounds__(256) void kfinal(const float* __restrict__ zi,
                                              const float* __restrict__ zj,
                                              const float* __restrict__ rnorm,
                                              const float* __restrict__ rowsum,
                                              float* __restrict__ out) {
  int t = threadIdx.x;
  int w = t >> 6, l = t & 63;
  float accum = 0.f;
#pragma unroll
  for (int sw = 0; sw < 4; ++sw) {
    int r = blockIdx.x * 4 + w + sw * 1024;    // pair index 0..HALFN-1
    const float* zr = zi + (size_t)r * DIM;
    const float* zp = zj + (size_t)r * DIM;
    float dot = 0.f;
#pragma unroll
    for (int j = 0; j < 4; ++j) {
      float4 a = ((const float4*)zr)[j * 64 + l];
      float4 b = ((const float4*)zp)[j * 64 + l];
      dot += a.x*b.x + a.y*b.y + a.z*b.z + a.w*b.w;
    }
    for (int m = 32; m; m >>= 1) dot += __shfl_xor(dot, m);
    if (l == 0) {
      float lse_r = logf(rowsum[r]) + INV_T;
      float lse_p = logf(rowsum[r + HALFN]) + INV_T;
      float pos = dot * rnorm[r] * rnorm[r + HALFN] * INV_T;
      accum += lse_r + lse_p - 2.0f * pos;
    }
  }
  __shared__ float part[4];
  if (l == 0) part[w] = accum;
  __syncthreads();
  if (t == 0)
    atomicAdd(out, (part[0] + part[1] + part[2] + part[3]) * (1.0f / (float)NROWS));
}

// ---------------- launch ----------------
extern "C" void kernel_launch(void* const* d_in, const int* in_sizes, int n_in,
                              void* d_out, int out_size, void* d_ws, size_t ws_size,
                              hipStream_t stream) {
  const float* zi = (const float*)d_in[0];
  const float* zj = (const float*)d_in[1];
  float* out = (float*)d_out;
  char* ws = (char*)d_ws;
  __bf16* znb   = (__bf16*)ws;                                   // 16 MB
  float*  rnorm = (float*)(ws + (size_t)NROWS * DIM * 2);        // 32 KB
  float*  rowsum= (float*)(ws + (size_t)NROWS * DIM * 2 + NROWS * 4);

  (void)hipMemsetAsync(rowsum, 0, NROWS * sizeof(float), stream);
  (void)hipMemsetAsync(out, 0, sizeof(float), stream);

  knorm<<<NROWS, 256, 0, stream>>>(zi, zj, znb, rnorm);
  ksim<<<32 * 32, 512, 0, stream>>>(znb, rowsum);
  kfinal<<<256, 256, 0, stream>>>(zi, zj, rnorm, rowsum, out);
}

// Round 8
// 283.767 us; speedup vs baseline: 1.3581x; 1.0075x over previous
//
#include <hip/hip_runtime.h>
#include <hip/hip_bf16.h>
#include <stdint.h>
#include <math.h>

// NT-Xent contrastive loss, N=4096, D=1024, 2N=8192 rows.
// knorm (normalize + bf16 + zero side-buffers) -> ksim (m97-structure 128^2
// bf16 MFMA GEMM, BK=32, 3 blocks/CU overlap, swizzled LDS + exp + rowsum)
// -> kfinal (exact fp32 positives per pair + lse + mean).

#define NROWS 8192
#define HALFN 4096
#define DIM   1024
#define INV_T 14.285714285714286f   // 1/0.07; fixed LSE shift C (sim <= 1/T)

typedef __bf16 bf16x8 __attribute__((ext_vector_type(8)));
typedef float  f32x4  __attribute__((ext_vector_type(4)));

__device__ __forceinline__ unsigned short f2bf(float x) {
  union { float f; uint32_t u; } c; c.f = x;
  uint32_t u = c.u;
  return (unsigned short)((u + 0x7FFFu + ((u >> 16) & 1u)) >> 16);
}

__device__ __forceinline__ void gload16(const void* g, void* lds) {
  __builtin_amdgcn_global_load_lds(
      (const __attribute__((address_space(1))) unsigned int*)g,
      (__attribute__((address_space(3))) unsigned int*)lds,
      16, 0, 0);
}

// ---------------- kernel A: row L2-normalize + bf16 convert ----------------
// Also zeroes rowsum[r] and (block 0) the output scalar: replaces 2 memsets.
__global__ __launch_bounds__(256) void knorm(const float* __restrict__ zi,
                                             const float* __restrict__ zj,
                                             __bf16* __restrict__ znb,
                                             float* __restrict__ rnorm,
                                             float* __restrict__ rowsum,
                                             float* __restrict__ out) {
  int r = blockIdx.x;
  const float* z = (r < HALFN) ? (zi + (size_t)r * DIM)
                               : (zj + (size_t)(r - HALFN) * DIM);
  int t = threadIdx.x;
  float4 v = ((const float4*)z)[t];
  float ss = v.x*v.x + v.y*v.y + v.z*v.z + v.w*v.w;
  for (int m = 32; m; m >>= 1) ss += __shfl_xor(ss, m);
  __shared__ float wss[4];
  if ((t & 63) == 0) wss[t >> 6] = ss;
  __syncthreads();
  float nrm = sqrtf(wss[0] + wss[1] + wss[2] + wss[3]);
  nrm = fmaxf(nrm, 1e-8f);
  float rn = 1.0f / nrm;
  if (t == 0) {
    rnorm[r] = rn;
    rowsum[r] = 0.f;
    if (r == 0) out[0] = 0.f;
  }
  ushort4 o;
  o.x = f2bf(v.x * rn); o.y = f2bf(v.y * rn);
  o.z = f2bf(v.z * rn); o.w = f2bf(v.w * rn);
  ((ushort4*)znb)[(size_t)r * (DIM / 4) + t] = o;
}

// ---------------- kernel C: m97-structure 128^2 sim GEMM ----------------
// BM=BN=128, BK=32, 4 waves (2x2, each 64x64 out, acc[4][4]).
// LDS 16KB single-buffered: As[128][32], Bs[128][32], row stride 64B.
// Chunk swizzle: LDS[r][c] = G[r][c ^ ((r>>1)&3)] -> frag ds_read_b128 hits
// (row-parity x chunk) = 8 bank-slots x 2 lanes = 2-way (free, m136).
// Loop: stage (4 gload_lds/thread) -> __syncthreads (vmcnt drain) ->
//       8 ds_read_b128 -> 16 MFMA -> __syncthreads.  Cross-block overlap
// (3 blocks/CU) hides the drain (m97/m114 mechanism).
__global__ __launch_bounds__(256, 3) void ksim(const __bf16* __restrict__ znb,
                                               float* __restrict__ rowsum) {
  __shared__ __align__(16) __bf16 As[128 * 32];   // 8 KB
  __shared__ __align__(16) __bf16 Bs[128 * 32];   // 8 KB

  // bijective XCD swizzle: 4096 blocks, 8 XCDs, 512 per XCD
  unsigned bid = blockIdx.x;
  unsigned swz = (bid & 7u) * 512u + (bid >> 3);
  unsigned rb = swz >> 6;          // 0..63 row tile
  unsigned cb = swz & 63u;         // 0..63 col tile

  int t = threadIdx.x;
  int w = t >> 6, l = t & 63;
  int wr = w >> 1, wc = w & 1;     // 2x2 wave grid, each wave 64x64
  int lr = l & 15, lg = l >> 4;

  const __bf16* Aor = znb + (size_t)rb * 128 * DIM;
  const __bf16* Bor = znb + (size_t)cb * 128 * DIM;

  int srow = l >> 2;                       // staging: lane's row offset (0..15)
  int sck  = (l & 3) ^ ((l >> 3) & 3);     // pre-swizzled global chunk
  int rsw  = (lr >> 1) & 3;                // read-side row swizzle term

  f32x4 acc[4][4] = {};

  for (int kt = 0; kt < 32; ++kt) {
    int k0 = kt * 32;
    // stage 16KB: i=0,1 -> A rows 0..63 / 64..127 (and same for B).
    // LDS dest wave-uniform base + lane*16 (linear); source pre-swizzled.
#pragma unroll
    for (int i = 0; i < 2; ++i) {
      int row = i * 64 + w * 16 + srow;
      gload16(Aor + (size_t)row * DIM + k0 + sck * 8, (char*)As + i * 4096 + w * 1024);
      gload16(Bor + (size_t)row * DIM + k0 + sck * 8, (char*)Bs + i * 4096 + w * 1024);
    }
    __syncthreads();                       // vmcnt drain: tile resident
    bf16x8 af[4], bg[4];
#pragma unroll
    for (int m = 0; m < 4; ++m) {
      int rowa = wr * 64 + m * 16 + lr;
      af[m] = *(const bf16x8*)((const char*)As + rowa * 64 + ((lg ^ rsw) * 16));
      int rowb = wc * 64 + m * 16 + lr;
      bg[m] = *(const bf16x8*)((const char*)Bs + rowb * 64 + ((lg ^ rsw) * 16));
    }
#pragma unroll
    for (int m = 0; m < 4; ++m)
#pragma unroll
      for (int n = 0; n < 4; ++n)
        acc[m][n] = __builtin_amdgcn_mfma_f32_16x16x32_bf16(af[m], bg[n], acc[m][n], 0, 0, 0);
    __syncthreads();                       // reads done before next stage
  }

  // epilogue: e = exp2((dot-1)*s2); diag masked; per-row sums -> atomics
  const float s2 = INV_T * 1.442695040888963f;
  int growb = (int)(rb * 128) + wr * 64;
  int gcolb = (int)(cb * 128) + wc * 64;
#pragma unroll
  for (int m = 0; m < 4; ++m) {
    float s[4] = {0.f, 0.f, 0.f, 0.f};
#pragma unroll
    for (int n = 0; n < 4; ++n) {
      int gcol = gcolb + n * 16 + lr;                  // C/D: col = lane&15
#pragma unroll
      for (int j = 0; j < 4; ++j) {
        int grow = growb + m * 16 + lg * 4 + j;        // row = (lane>>4)*4+j
        float e = exp2f(fmaf(acc[m][n][j], s2, -s2));
        if (grow == gcol) e = 0.f;
        s[j] += e;
      }
    }
#pragma unroll
    for (int j = 0; j < 4; ++j) {
      float v = s[j];
      v += __shfl_xor(v, 1);
      v += __shfl_xor(v, 2);
      v += __shfl_xor(v, 4);
      v += __shfl_xor(v, 8);
      if (lr == 0)
        atomicAdd(rowsum + growb + m * 16 + lg * 4 + j, v);
    }
  }
}

// ---------------- kernel D: positives + lse + mean, low atomic contention --
// 256 blocks x 4 sweeps; ONE same-address atomic per block.
__global__ __launch_bounds__(256) void kfinal(const float* __restrict__ zi,
                                              const float* __restrict__ zj,
                                              const float* __restrict__ rnorm,
                                              const float* __restrict__ rowsum,
                                              float* __restrict__ out) {
  int t = threadIdx.x;
  int w = t >> 6, l = t & 63;
  float accum = 0.f;
#pragma unroll
  for (int sw = 0; sw < 4; ++sw) {
    int r = blockIdx.x * 4 + w + sw * 1024;    // pair index 0..HALFN-1
    const float* zr = zi + (size_t)r * DIM;
    const float* zp = zj + (size_t)r * DIM;
    float dot = 0.f;
#pragma unroll
    for (int j = 0; j < 4; ++j) {
      float4 a = ((const float4*)zr)[j * 64 + l];
      float4 b = ((const float4*)zp)[j * 64 + l];
      dot += a.x*b.x + a.y*b.y + a.z*b.z + a.w*b.w;
    }
    for (int m = 32; m; m >>= 1) dot += __shfl_xor(dot, m);
    if (l == 0) {
      float lse_r = logf(rowsum[r]) + INV_T;
      float lse_p = logf(rowsum[r + HALFN]) + INV_T;
      float pos = dot * rnorm[r] * rnorm[r + HALFN] * INV_T;
      accum += lse_r + lse_p - 2.0f * pos;
    }
  }
  __shared__ float part[4];
  if (l == 0) part[w] = accum;
  __syncthreads();
  if (t == 0)
    atomicAdd(out, (part[0] + part[1] + part[2] + part[3]) * (1.0f / (float)NROWS));
}

// ---------------- launch ----------------
extern "C" void kernel_launch(void* const* d_in, const int* in_sizes, int n_in,
                              void* d_out, int out_size, void* d_ws, size_t ws_size,
                              hipStream_t stream) {
  const float* zi = (const float*)d_in[0];
  const float* zj = (const float*)d_in[1];
  float* out = (float*)d_out;
  char* ws = (char*)d_ws;
  __bf16* znb   = (__bf16*)ws;                                   // 16 MB
  float*  rnorm = (float*)(ws + (size_t)NROWS * DIM * 2);        // 32 KB
  float*  rowsum= (float*)(ws + (size_t)NROWS * DIM * 2 + NROWS * 4);

  knorm<<<NROWS, 256, 0, stream>>>(zi, zj, znb, rnorm, rowsum, out);
  ksim<<<64 * 64, 256, 0, stream>>>(znb, rowsum);
  kfinal<<<256, 256, 0, stream>>>(zi, zj, rnorm, rowsum, out);
}

// Round 9
// 190.746 us; speedup vs baseline: 2.0204x; 1.4877x over previous
//
#include <hip/hip_runtime.h>
#include <hip/hip_bf16.h>
#include <stdint.h>
#include <math.h>

// NT-Xent contrastive loss, N=4096, D=1024, 2N=8192 rows.
// knorm (normalize + bf16 + zero side-buffers) -> ksim (SYMMETRY-HALVED
// upper-triangle 128^2 bf16 MFMA GEMM; row+col sums per tile) -> kfinal.

#define NROWS 8192
#define HALFN 4096
#define DIM   1024
#define INV_T 14.285714285714286f   // 1/0.07; fixed LSE shift C (sim <= 1/T)

typedef __bf16 bf16x8 __attribute__((ext_vector_type(8)));
typedef float  f32x4  __attribute__((ext_vector_type(4)));

__device__ __forceinline__ unsigned short f2bf(float x) {
  union { float f; uint32_t u; } c; c.f = x;
  uint32_t u = c.u;
  return (unsigned short)((u + 0x7FFFu + ((u >> 16) & 1u)) >> 16);
}

__device__ __forceinline__ void gload16(const void* g, void* lds) {
  __builtin_amdgcn_global_load_lds(
      (const __attribute__((address_space(1))) unsigned int*)g,
      (__attribute__((address_space(3))) unsigned int*)lds,
      16, 0, 0);
}

// ---------------- kernel A: row L2-normalize + bf16 convert ----------------
__global__ __launch_bounds__(256) void knorm(const float* __restrict__ zi,
                                             const float* __restrict__ zj,
                                             __bf16* __restrict__ znb,
                                             float* __restrict__ rnorm,
                                             float* __restrict__ rowsum,
                                             float* __restrict__ out) {
  int r = blockIdx.x;
  const float* z = (r < HALFN) ? (zi + (size_t)r * DIM)
                               : (zj + (size_t)(r - HALFN) * DIM);
  int t = threadIdx.x;
  float4 v = ((const float4*)z)[t];
  float ss = v.x*v.x + v.y*v.y + v.z*v.z + v.w*v.w;
  for (int m = 32; m; m >>= 1) ss += __shfl_xor(ss, m);
  __shared__ float wss[4];
  if ((t & 63) == 0) wss[t >> 6] = ss;
  __syncthreads();
  float nrm = sqrtf(wss[0] + wss[1] + wss[2] + wss[3]);
  nrm = fmaxf(nrm, 1e-8f);
  float rn = 1.0f / nrm;
  if (t == 0) {
    rnorm[r] = rn;
    rowsum[r] = 0.f;
    if (r == 0) out[0] = 0.f;
  }
  ushort4 o;
  o.x = f2bf(v.x * rn); o.y = f2bf(v.y * rn);
  o.z = f2bf(v.z * rn); o.w = f2bf(v.w * rn);
  ((ushort4*)znb)[(size_t)r * (DIM / 4) + t] = o;
}

// ---------------- kernel C: upper-triangle 128^2 sim GEMM ----------------
// Identical GEMM core to round 8 (measured 660 TF): BM=BN=128, BK=32,
// 4 waves 2x2, 16KB LDS, chunk swizzle c ^= (r>>1)&3, 3 blocks/CU.
// NEW: only tiles rb<=cb (2080 of 4096). Off-diag tiles feed rowsum[R]
// via row-sums AND rowsum[C] via col-sums (sim symmetric). Diag tiles:
// row-sums only (col-sums would double count).
__global__ __launch_bounds__(256, 3) void ksim(const __bf16* __restrict__ znb,
                                               float* __restrict__ rowsum) {
  __shared__ __align__(16) __bf16 As[128 * 32];   // 8 KB
  __shared__ __align__(16) __bf16 Bs[128 * 32];   // 8 KB

  // bijective XCD swizzle over 2080 = 8 x 260 triangle tiles
  unsigned bid = blockIdx.x;
  unsigned u = (bid & 7u) * 260u + (bid >> 3);
  // invert s(rb) = rb*(129-rb)/2 <= u (fp32 hint + exact integer fixup)
  int rbI = (int)(0.5f * (129.0f - sqrtf(16641.0f - 8.0f * (float)u)));
  while ((rbI + 1) * (129 - (rbI + 1)) / 2 <= (int)u) ++rbI;
  while (rbI * (129 - rbI) / 2 > (int)u) --rbI;
  int cbI = rbI + ((int)u - rbI * (129 - rbI) / 2);

  int t = threadIdx.x;
  int w = t >> 6, l = t & 63;
  int wr = w >> 1, wc = w & 1;     // 2x2 wave grid, each wave 64x64
  int lr = l & 15, lg = l >> 4;

  const __bf16* Aor = znb + (size_t)rbI * 128 * DIM;
  const __bf16* Bor = znb + (size_t)cbI * 128 * DIM;

  int srow = l >> 2;                       // staging: lane's row offset (0..15)
  int sck  = (l & 3) ^ ((l >> 3) & 3);     // pre-swizzled global chunk
  int rsw  = (lr >> 1) & 3;                // read-side row swizzle term

  f32x4 acc[4][4] = {};

  for (int kt = 0; kt < 32; ++kt) {
    int k0 = kt * 32;
#pragma unroll
    for (int i = 0; i < 2; ++i) {
      int row = i * 64 + w * 16 + srow;
      gload16(Aor + (size_t)row * DIM + k0 + sck * 8, (char*)As + i * 4096 + w * 1024);
      gload16(Bor + (size_t)row * DIM + k0 + sck * 8, (char*)Bs + i * 4096 + w * 1024);
    }
    __syncthreads();                       // vmcnt drain: tile resident
    bf16x8 af[4], bg[4];
#pragma unroll
    for (int m = 0; m < 4; ++m) {
      int rowa = wr * 64 + m * 16 + lr;
      af[m] = *(const bf16x8*)((const char*)As + rowa * 64 + ((lg ^ rsw) * 16));
      int rowb = wc * 64 + m * 16 + lr;
      bg[m] = *(const bf16x8*)((const char*)Bs + rowb * 64 + ((lg ^ rsw) * 16));
    }
#pragma unroll
    for (int m = 0; m < 4; ++m)
#pragma unroll
      for (int n = 0; n < 4; ++n)
        acc[m][n] = __builtin_amdgcn_mfma_f32_16x16x32_bf16(af[m], bg[n], acc[m][n], 0, 0, 0);
    __syncthreads();                       // reads done before next stage
  }

  // epilogue: e = exp2((dot-1)*s2); diag masked; row sums + col sums
  const float s2 = INV_T * 1.442695040888963f;
  int growb = rbI * 128 + wr * 64;
  int gcolb = cbI * 128 + wc * 64;
  float csn[4] = {0.f, 0.f, 0.f, 0.f};     // col partials (cols n*16+lr)
#pragma unroll
  for (int m = 0; m < 4; ++m) {
    float s[4] = {0.f, 0.f, 0.f, 0.f};
#pragma unroll
    for (int n = 0; n < 4; ++n) {
      int gcol = gcolb + n * 16 + lr;                  // C/D: col = lane&15
#pragma unroll
      for (int j = 0; j < 4; ++j) {
        int grow = growb + m * 16 + lg * 4 + j;        // row = (lane>>4)*4+j
        float e = exp2f(fmaf(acc[m][n][j], s2, -s2));
        if (grow == gcol) e = 0.f;                     // diag (rb==cb only)
        s[j] += e;
        csn[n] += e;
      }
    }
#pragma unroll
    for (int j = 0; j < 4; ++j) {
      float v = s[j];
      v += __shfl_xor(v, 1);
      v += __shfl_xor(v, 2);
      v += __shfl_xor(v, 4);
      v += __shfl_xor(v, 8);
      if (lr == 0)
        atomicAdd(rowsum + growb + m * 16 + lg * 4 + j, v);
    }
  }
  if (rbI != cbI) {                        // transpose contribution
#pragma unroll
    for (int n = 0; n < 4; ++n) {
      float v = csn[n];
      v += __shfl_xor(v, 16);
      v += __shfl_xor(v, 32);
      if (lg == 0)
        atomicAdd(rowsum + gcolb + n * 16 + lr, v);
    }
  }
}

// ---------------- kernel D: positives + lse + mean, low atomic contention --
__global__ __launch_bounds__(256) void kfinal(const float* __restrict__ zi,
                                              const float* __restrict__ zj,
                                              const float* __restrict__ rnorm,
                                              const float* __restrict__ rowsum,
                                              float* __restrict__ out) {
  int t = threadIdx.x;
  int w = t >> 6, l = t & 63;
  float accum = 0.f;
#pragma unroll
  for (int sw = 0; sw < 4; ++sw) {
    int r = blockIdx.x * 4 + w + sw * 1024;    // pair index 0..HALFN-1
    const float* zr = zi + (size_t)r * DIM;
    const float* zp = zj + (size_t)r * DIM;
    float dot = 0.f;
#pragma unroll
    for (int j = 0; j < 4; ++j) {
      float4 a = ((const float4*)zr)[j * 64 + l];
      float4 b = ((const float4*)zp)[j * 64 + l];
      dot += a.x*b.x + a.y*b.y + a.z*b.z + a.w*b.w;
    }
    for (int m = 32; m; m >>= 1) dot += __shfl_xor(dot, m);
    if (l == 0) {
      float lse_r = logf(rowsum[r]) + INV_T;
      float lse_p = logf(rowsum[r + HALFN]) + INV_T;
      float pos = dot * rnorm[r] * rnorm[r + HALFN] * INV_T;
      accum += lse_r + lse_p - 2.0f * pos;
    }
  }
  __shared__ float part[4];
  if (l == 0) part[w] = accum;
  __syncthreads();
  if (t == 0)
    atomicAdd(out, (part[0] + part[1] + part[2] + part[3]) * (1.0f / (float)NROWS));
}

// ---------------- launch ----------------
extern "C" void kernel_launch(void* const* d_in, const int* in_sizes, int n_in,
                              void* d_out, int out_size, void* d_ws, size_t ws_size,
                              hipStream_t stream) {
  const float* zi = (const float*)d_in[0];
  const float* zj = (const float*)d_in[1];
  float* out = (float*)d_out;
  char* ws = (char*)d_ws;
  __bf16* znb   = (__bf16*)ws;                                   // 16 MB
  float*  rnorm = (float*)(ws + (size_t)NROWS * DIM * 2);        // 32 KB
  float*  rowsum= (float*)(ws + (size_t)NROWS * DIM * 2 + NROWS * 4);

  knorm<<<NROWS, 256, 0, stream>>>(zi, zj, znb, rnorm, rowsum, out);
  ksim<<<2080, 256, 0, stream>>>(znb, rowsum);
  kfinal<<<256, 256, 0, stream>>>(zi, zj, rnorm, rowsum, out);
}

// Round 10
// 187.538 us; speedup vs baseline: 2.0550x; 1.0171x over previous
//
#include <hip/hip_runtime.h>
#include <hip/hip_bf16.h>
#include <stdint.h>
#include <math.h>

// NT-Xent contrastive loss, N=4096, D=1024, 2N=8192 rows.
// knorm (normalize + bf16 + zero side-buffers) -> ksim (SYMMETRY-HALVED
// upper-triangle 128^2 bf16 MFMA GEMM; row+col sums per tile; 4 blocks/CU)
// -> kfinal (exact fp32 positives per pair + lse + mean).

#define NROWS 8192
#define HALFN 4096
#define DIM   1024
#define INV_T 14.285714285714286f   // 1/0.07; fixed LSE shift C (sim <= 1/T)

typedef __bf16 bf16x8 __attribute__((ext_vector_type(8)));
typedef float  f32x4  __attribute__((ext_vector_type(4)));

__device__ __forceinline__ unsigned short f2bf(float x) {
  union { float f; uint32_t u; } c; c.f = x;
  uint32_t u = c.u;
  return (unsigned short)((u + 0x7FFFu + ((u >> 16) & 1u)) >> 16);
}

__device__ __forceinline__ void gload16(const void* g, void* lds) {
  __builtin_amdgcn_global_load_lds(
      (const __attribute__((address_space(1))) unsigned int*)g,
      (__attribute__((address_space(3))) unsigned int*)lds,
      16, 0, 0);
}

// ---------------- kernel A: row L2-normalize + bf16 convert ----------------
__global__ __launch_bounds__(256) void knorm(const float* __restrict__ zi,
                                             const float* __restrict__ zj,
                                             __bf16* __restrict__ znb,
                                             float* __restrict__ rnorm,
                                             float* __restrict__ rowsum,
                                             float* __restrict__ out) {
  int r = blockIdx.x;
  const float* z = (r < HALFN) ? (zi + (size_t)r * DIM)
                               : (zj + (size_t)(r - HALFN) * DIM);
  int t = threadIdx.x;
  float4 v = ((const float4*)z)[t];
  float ss = v.x*v.x + v.y*v.y + v.z*v.z + v.w*v.w;
  for (int m = 32; m; m >>= 1) ss += __shfl_xor(ss, m);
  __shared__ float wss[4];
  if ((t & 63) == 0) wss[t >> 6] = ss;
  __syncthreads();
  float nrm = sqrtf(wss[0] + wss[1] + wss[2] + wss[3]);
  nrm = fmaxf(nrm, 1e-8f);
  float rn = 1.0f / nrm;
  if (t == 0) {
    rnorm[r] = rn;
    rowsum[r] = 0.f;
    if (r == 0) out[0] = 0.f;
  }
  ushort4 o;
  o.x = f2bf(v.x * rn); o.y = f2bf(v.y * rn);
  o.z = f2bf(v.z * rn); o.w = f2bf(v.w * rn);
  ((ushort4*)znb)[(size_t)r * (DIM / 4) + t] = o;
}

// ---------------- kernel C: upper-triangle 128^2 sim GEMM ----------------
// Round-9 measured core (115 us), single change: launch_bounds (256,4)
// -> 4 blocks/CU (regs 124 <= 128, LDS 64KB). m114: cross-block overlap
// is what hides the 2-barrier drain; +33% resident blocks strengthens it.
__global__ __launch_bounds__(256, 4) void ksim(const __bf16* __restrict__ znb,
                                               float* __restrict__ rowsum) {
  __shared__ __align__(16) __bf16 As[128 * 32];   // 8 KB
  __shared__ __align__(16) __bf16 Bs[128 * 32];   // 8 KB

  // bijective XCD swizzle over 2080 = 8 x 260 triangle tiles
  unsigned bid = blockIdx.x;
  unsigned u = (bid & 7u) * 260u + (bid >> 3);
  // invert s(rb) = rb*(129-rb)/2 <= u (fp32 hint + exact integer fixup)
  int rbI = (int)(0.5f * (129.0f - sqrtf(16641.0f - 8.0f * (float)u)));
  while ((rbI + 1) * (129 - (rbI + 1)) / 2 <= (int)u) ++rbI;
  while (rbI * (129 - rbI) / 2 > (int)u) --rbI;
  int cbI = rbI + ((int)u - rbI * (129 - rbI) / 2);

  int t = threadIdx.x;
  int w = t >> 6, l = t & 63;
  int wr = w >> 1, wc = w & 1;     // 2x2 wave grid, each wave 64x64
  int lr = l & 15, lg = l >> 4;

  const __bf16* Aor = znb + (size_t)rbI * 128 * DIM;
  const __bf16* Bor = znb + (size_t)cbI * 128 * DIM;

  int srow = l >> 2;                       // staging: lane's row offset (0..15)
  int sck  = (l & 3) ^ ((l >> 3) & 3);     // pre-swizzled global chunk
  int rsw  = (lr >> 1) & 3;                // read-side row swizzle term

  f32x4 acc[4][4] = {};

  for (int kt = 0; kt < 32; ++kt) {
    int k0 = kt * 32;
#pragma unroll
    for (int i = 0; i < 2; ++i) {
      int row = i * 64 + w * 16 + srow;
      gload16(Aor + (size_t)row * DIM + k0 + sck * 8, (char*)As + i * 4096 + w * 1024);
      gload16(Bor + (size_t)row * DIM + k0 + sck * 8, (char*)Bs + i * 4096 + w * 1024);
    }
    __syncthreads();                       // vmcnt drain: tile resident
    bf16x8 af[4], bg[4];
#pragma unroll
    for (int m = 0; m < 4; ++m) {
      int rowa = wr * 64 + m * 16 + lr;
      af[m] = *(const bf16x8*)((const char*)As + rowa * 64 + ((lg ^ rsw) * 16));
      int rowb = wc * 64 + m * 16 + lr;
      bg[m] = *(const bf16x8*)((const char*)Bs + rowb * 64 + ((lg ^ rsw) * 16));
    }
#pragma unroll
    for (int m = 0; m < 4; ++m)
#pragma unroll
      for (int n = 0; n < 4; ++n)
        acc[m][n] = __builtin_amdgcn_mfma_f32_16x16x32_bf16(af[m], bg[n], acc[m][n], 0, 0, 0);
    __syncthreads();                       // reads done before next stage
  }

  // epilogue: e = exp2((dot-1)*s2); diag masked; row sums + col sums
  const float s2 = INV_T * 1.442695040888963f;
  int growb = rbI * 128 + wr * 64;
  int gcolb = cbI * 128 + wc * 64;
  float csn[4] = {0.f, 0.f, 0.f, 0.f};     // col partials (cols n*16+lr)
#pragma unroll
  for (int m = 0; m < 4; ++m) {
    float s[4] = {0.f, 0.f, 0.f, 0.f};
#pragma unroll
    for (int n = 0; n < 4; ++n) {
      int gcol = gcolb + n * 16 + lr;                  // C/D: col = lane&15
#pragma unroll
      for (int j = 0; j < 4; ++j) {
        int grow = growb + m * 16 + lg * 4 + j;        // row = (lane>>4)*4+j
        float e = exp2f(fmaf(acc[m][n][j], s2, -s2));
        if (grow == gcol) e = 0.f;                     // diag (rb==cb only)
        s[j] += e;
        csn[n] += e;
      }
    }
#pragma unroll
    for (int j = 0; j < 4; ++j) {
      float v = s[j];
      v += __shfl_xor(v, 1);
      v += __shfl_xor(v, 2);
      v += __shfl_xor(v, 4);
      v += __shfl_xor(v, 8);
      if (lr == 0)
        atomicAdd(rowsum + growb + m * 16 + lg * 4 + j, v);
    }
  }
  if (rbI != cbI) {                        // transpose contribution
#pragma unroll
    for (int n = 0; n < 4; ++n) {
      float v = csn[n];
      v += __shfl_xor(v, 16);
      v += __shfl_xor(v, 32);
      if (lg == 0)
        atomicAdd(rowsum + gcolb + n * 16 + lr, v);
    }
  }
}

// ---------------- kernel D: positives + lse + mean, low atomic contention --
__global__ __launch_bounds__(256) void kfinal(const float* __restrict__ zi,
                                              const float* __restrict__ zj,
                                              const float* __restrict__ rnorm,
                                              const float* __restrict__ rowsum,
                                              float* __restrict__ out) {
  int t = threadIdx.x;
  int w = t >> 6, l = t & 63;
  float accum = 0.f;
#pragma unroll
  for (int sw = 0; sw < 4; ++sw) {
    int r = blockIdx.x * 4 + w + sw * 1024;    // pair index 0..HALFN-1
    const float* zr = zi + (size_t)r * DIM;
    const float* zp = zj + (size_t)r * DIM;
    float dot = 0.f;
#pragma unroll
    for (int j = 0; j < 4; ++j) {
      float4 a = ((const float4*)zr)[j * 64 + l];
      float4 b = ((const float4*)zp)[j * 64 + l];
      dot += a.x*b.x + a.y*b.y + a.z*b.z + a.w*b.w;
    }
    for (int m = 32; m; m >>= 1) dot += __shfl_xor(dot, m);
    if (l == 0) {
      float lse_r = logf(rowsum[r]) + INV_T;
      float lse_p = logf(rowsum[r + HALFN]) + INV_T;
      float pos = dot * rnorm[r] * rnorm[r + HALFN] * INV_T;
      accum += lse_r + lse_p - 2.0f * pos;
    }
  }
  __shared__ float part[4];
  if (l == 0) part[w] = accum;
  __syncthreads();
  if (t == 0)
    atomicAdd(out, (part[0] + part[1] + part[2] + part[3]) * (1.0f / (float)NROWS));
}

// ---------------- launch ----------------
extern "C" void kernel_launch(void* const* d_in, const int* in_sizes, int n_in,
                              void* d_out, int out_size, void* d_ws, size_t ws_size,
                              hipStream_t stream) {
  const float* zi = (const float*)d_in[0];
  const float* zj = (const float*)d_in[1];
  float* out = (float*)d_out;
  char* ws = (char*)d_ws;
  __bf16* znb   = (__bf16*)ws;                                   // 16 MB
  float*  rnorm = (float*)(ws + (size_t)NROWS * DIM * 2);        // 32 KB
  float*  rowsum= (float*)(ws + (size_t)NROWS * DIM * 2 + NROWS * 4);

  knorm<<<NROWS, 256, 0, stream>>>(zi, zj, znb, rnorm, rowsum, out);
  ksim<<<2080, 256, 0, stream>>>(znb, rowsum);
  kfinal<<<256, 256, 0, stream>>>(zi, zj, rnorm, rowsum, out);
}